// Round 1
// baseline (2800.131 us; speedup 1.0000x reference)
//
#include <hip/hip_runtime.h>

#define BT   4      // batch tile per block
#define HID  64
#define G4   256    // 4*HID
#define SEQ  512
#define NOUT 12

typedef float v16f __attribute__((ext_vector_type(16)));

__device__ __forceinline__ float sigf(float x)  { return 1.f / (1.f + __expf(-x)); }
__device__ __forceinline__ float tanhf_fast(float x) { return 1.f - 2.f / (1.f + __expf(2.f * x)); }

// Load 16 weights (row `row`, cols j0..j0+15 of a [256,64] matrix) into one v16f.
#define LOAD16(M, row, V)                                              \
    {                                                                  \
        const float4* p4 = (const float4*)&M[(row) * HID + j0];        \
        _Pragma("unroll")                                              \
        for (int j = 0; j < 4; ++j) {                                  \
            float4 q = p4[j];                                          \
            V[4*j+0] = q.x; V[4*j+1] = q.y;                            \
            V[4*j+2] = q.z; V[4*j+3] = q.w;                            \
        }                                                              \
    }

// r=2 rows/thread, s=4 K-split: 512 threads, 96 weight VGPRs/thread,
// each LDS float4 broadcast feeds 8 FMAs, 4-lane shuffle reduce per gate.
__global__ void __launch_bounds__(512) __attribute__((amdgpu_waves_per_eu(4, 4)))
lstm2_fused(
    const float* __restrict__ x,      // [B, SEQ, 1]
    const float* __restrict__ w_ih0,  // [256, 1]
    const float* __restrict__ w_hh0,  // [256, 64]
    const float* __restrict__ b_ih0,  // [256]
    const float* __restrict__ b_hh0,  // [256]
    const float* __restrict__ w_ih1,  // [256, 64]
    const float* __restrict__ w_hh1,  // [256, 64]
    const float* __restrict__ b_ih1,  // [256]
    const float* __restrict__ b_hh1,  // [256]
    const float* __restrict__ fc_w,   // [12, 64]
    const float* __restrict__ fc_b,   // [12]
    float* __restrict__ out)          // [B, 12]
{
    __shared__ float xs[BT][SEQ];    // 8 KB
    __shared__ float h0s[BT][HID];   // 1 KB
    __shared__ float h1s[BT][HID];   // 1 KB
    __shared__ float gs[BT][G4];     // 4 KB

    const int tid = threadIdx.x;
    const int ks  = tid & 3;          // K-quarter (0..3), intra-quad lanes
    const int p   = tid >> 2;         // row-pair index (0..127)
    const int g0  = p;                // gate row 0
    const int g1  = p + 128;          // gate row 1
    const int j0  = ks * 16;          // K-slice start
    const int b0  = blockIdx.x * BT;

    // ---- loop-invariant weight slices: 6 x v16f = 96 VGPRs ----
    v16f W00 = {}, W01 = {};   // w_hh0 rows g0,g1
    v16f WI0 = {}, WI1 = {};   // w_ih1 rows g0,g1
    v16f W10 = {}, W11 = {};   // w_hh1 rows g0,g1
    LOAD16(w_hh0, g0, W00); LOAD16(w_hh0, g1, W01);
    LOAD16(w_ih1, g0, WI0); LOAD16(w_ih1, g1, WI1);
    LOAD16(w_hh1, g0, W10); LOAD16(w_hh1, g1, W11);

    const float wih0g0 = w_ih0[g0];
    const float wih0g1 = w_ih0[g1];
    const float bias00 = b_ih0[g0] + b_hh0[g0];
    const float bias01 = b_ih0[g1] + b_hh0[g1];
    const float bias10 = b_ih1[g0] + b_hh1[g0];
    const float bias11 = b_ih1[g1] + b_hh1[g1];

    // ---- stage this block's x tile into LDS ----
    for (int i = tid; i < BT * SEQ; i += 512) {
        int b = i >> 9, t = i & (SEQ - 1);
        xs[b][t] = x[(size_t)(b0 + b) * SEQ + t];
    }
    for (int i = tid; i < BT * HID; i += 512) {
        ((float*)h0s)[i] = 0.f;
        ((float*)h1s)[i] = 0.f;
    }
    const int eb = tid >> 6;     // batch (elementwise phase, tid<256 only)
    const int ej = tid & 63;     // hidden unit
    float c0 = 0.f, c1 = 0.f;
    __syncthreads();

    for (int t = 0; t < SEQ; ++t) {
        float a0[BT], a1[BT];

        // ===== layer 0 partial: a{0,1}[b] = h0[j0..j0+15] . w_hh0[g{0,1}][j0..] =====
#pragma unroll
        for (int b = 0; b < BT; ++b) { a0[b] = 0.f; a1[b] = 0.f; }
#pragma unroll
        for (int i = 0; i < 16; i += 4) {
#pragma unroll
            for (int b = 0; b < BT; ++b) {
                float4 hv = *(const float4*)&h0s[b][j0 + i];   // 4-chunk multicast, conflict-free
                a0[b] = fmaf(hv.x, W00[i+0], a0[b]);
                a0[b] = fmaf(hv.y, W00[i+1], a0[b]);
                a0[b] = fmaf(hv.z, W00[i+2], a0[b]);
                a0[b] = fmaf(hv.w, W00[i+3], a0[b]);
                a1[b] = fmaf(hv.x, W01[i+0], a1[b]);
                a1[b] = fmaf(hv.y, W01[i+1], a1[b]);
                a1[b] = fmaf(hv.z, W01[i+2], a1[b]);
                a1[b] = fmaf(hv.w, W01[i+3], a1[b]);
            }
        }
        // reduce across the 4 K-slice lanes (intra-quad butterfly)
#pragma unroll
        for (int b = 0; b < BT; ++b) {
            a0[b] += __shfl_xor(a0[b], 1);
            a0[b] += __shfl_xor(a0[b], 2);
            a1[b] += __shfl_xor(a1[b], 1);
            a1[b] += __shfl_xor(a1[b], 2);
        }
        if (ks == 0) {
#pragma unroll
            for (int b = 0; b < BT; ++b) {
                gs[b][g0] = a0[b] + fmaf(xs[b][t], wih0g0, bias00);
                gs[b][g1] = a1[b] + fmaf(xs[b][t], wih0g1, bias01);
            }
        }
        __syncthreads();

        // ===== elementwise 0 (waves 0-3 only; c0 in registers) =====
        if (tid < 256) {
            float ig = sigf(gs[eb][ej]);
            float fg = sigf(gs[eb][64 + ej]);
            float gg = tanhf_fast(gs[eb][128 + ej]);
            float og = sigf(gs[eb][192 + ej]);
            c0 = fg * c0 + ig * gg;
            h0s[eb][ej] = og * tanhf_fast(c0);
        }
        __syncthreads();

        // ===== layer 1 partial: a[b] = h0_new . w_ih1 + h1_old . w_hh1 (K-slice) =====
#pragma unroll
        for (int b = 0; b < BT; ++b) { a0[b] = 0.f; a1[b] = 0.f; }
#pragma unroll
        for (int i = 0; i < 16; i += 4) {
#pragma unroll
            for (int b = 0; b < BT; ++b) {
                float4 hv  = *(const float4*)&h0s[b][j0 + i];
                float4 h1v = *(const float4*)&h1s[b][j0 + i];
                a0[b] = fmaf(hv.x,  WI0[i+0], a0[b]);
                a0[b] = fmaf(hv.y,  WI0[i+1], a0[b]);
                a0[b] = fmaf(hv.z,  WI0[i+2], a0[b]);
                a0[b] = fmaf(hv.w,  WI0[i+3], a0[b]);
                a0[b] = fmaf(h1v.x, W10[i+0], a0[b]);
                a0[b] = fmaf(h1v.y, W10[i+1], a0[b]);
                a0[b] = fmaf(h1v.z, W10[i+2], a0[b]);
                a0[b] = fmaf(h1v.w, W10[i+3], a0[b]);
                a1[b] = fmaf(hv.x,  WI1[i+0], a1[b]);
                a1[b] = fmaf(hv.y,  WI1[i+1], a1[b]);
                a1[b] = fmaf(hv.z,  WI1[i+2], a1[b]);
                a1[b] = fmaf(hv.w,  WI1[i+3], a1[b]);
                a1[b] = fmaf(h1v.x, W11[i+0], a1[b]);
                a1[b] = fmaf(h1v.y, W11[i+1], a1[b]);
                a1[b] = fmaf(h1v.z, W11[i+2], a1[b]);
                a1[b] = fmaf(h1v.w, W11[i+3], a1[b]);
            }
        }
#pragma unroll
        for (int b = 0; b < BT; ++b) {
            a0[b] += __shfl_xor(a0[b], 1);
            a0[b] += __shfl_xor(a0[b], 2);
            a1[b] += __shfl_xor(a1[b], 1);
            a1[b] += __shfl_xor(a1[b], 2);
        }
        if (ks == 0) {
#pragma unroll
            for (int b = 0; b < BT; ++b) {
                gs[b][g0] = a0[b] + bias10;
                gs[b][g1] = a1[b] + bias11;
            }
        }
        __syncthreads();

        // ===== elementwise 1 =====
        if (tid < 256) {
            float ig = sigf(gs[eb][ej]);
            float fg = sigf(gs[eb][64 + ej]);
            float gg = tanhf_fast(gs[eb][128 + ej]);
            float og = sigf(gs[eb][192 + ej]);
            c1 = fg * c1 + ig * gg;
            h1s[eb][ej] = og * tanhf_fast(c1);
        }
        __syncthreads();
    }

    // ===== final projection: out[b][o] = fc_b[o] + h1 . fc_w[o] =====
    if (tid < BT * NOUT) {
        int b = tid / NOUT, o = tid % NOUT;
        float acc = fc_b[o];
#pragma unroll
        for (int j = 0; j < HID; ++j)
            acc = fmaf(fc_w[o * HID + j], h1s[b][j], acc);
        out[(size_t)(b0 + b) * NOUT + o] = acc;
    }
}

extern "C" void kernel_launch(void* const* d_in, const int* in_sizes, int n_in,
                              void* d_out, int out_size, void* d_ws, size_t ws_size,
                              hipStream_t stream) {
    const float* x     = (const float*)d_in[0];
    const float* w_ih0 = (const float*)d_in[1];
    const float* w_hh0 = (const float*)d_in[2];
    const float* b_ih0 = (const float*)d_in[3];
    const float* b_hh0 = (const float*)d_in[4];
    const float* w_ih1 = (const float*)d_in[5];
    const float* w_hh1 = (const float*)d_in[6];
    const float* b_ih1 = (const float*)d_in[7];
    const float* b_hh1 = (const float*)d_in[8];
    const float* fc_w  = (const float*)d_in[9];
    const float* fc_b  = (const float*)d_in[10];

    const int B = in_sizes[0] / SEQ;          // 2048
    dim3 grid(B / BT);                        // 512 blocks -> 2 blocks/CU (16 waves/CU)
    lstm2_fused<<<grid, 512, 0, stream>>>(x, w_ih0, w_hh0, b_ih0, b_hh0,
                                          w_ih1, w_hh1, b_ih1, b_hh1,
                                          fc_w, fc_b, (float*)d_out);
}

// Round 2
// 1945.345 us; speedup vs baseline: 1.4394x; 1.4394x over previous
//
#include <hip/hip_runtime.h>

#define BT   4      // batch tile per block
#define HID  64
#define G4   256    // 4*HID
#define SEQ  512
#define NOUT 12

typedef float v16f __attribute__((ext_vector_type(16)));

__device__ __forceinline__ float sigf(float x)  { return 1.f / (1.f + __expf(-x)); }
__device__ __forceinline__ float tanhf_fast(float x) { return 1.f - 2.f / (1.f + __expf(2.f * x)); }

// Load 64 weights (row g of a [256,64] matrix) into four v16f SSA vectors.
#define LOAD_ROW(M, V0, V1, V2, V3)                                        \
    {                                                                      \
        const float4* p = (const float4*)&M[g * HID];                      \
        _Pragma("unroll")                                                  \
        for (int c = 0; c < 4; ++c) {                                      \
            v16f& D = (c == 0) ? V0 : (c == 1) ? V1 : (c == 2) ? V2 : V3;  \
            _Pragma("unroll")                                              \
            for (int j = 0; j < 4; ++j) {                                  \
                float4 q = p[c * 4 + j];                                   \
                D[4 * j + 0] = q.x; D[4 * j + 1] = q.y;                    \
                D[4 * j + 2] = q.z; D[4 * j + 3] = q.w;                    \
            }                                                              \
        }                                                                  \
    }

// Two-layer software pipeline: one gemm phase computes gates0(t+1) AND gates1(t)
// (both read the same h0(t)); one elementwise phase retires both layers.
// 2 barriers/step instead of 4; h0 LDS-read once instead of twice.
__global__ void __launch_bounds__(256) __attribute__((amdgpu_waves_per_eu(2, 2)))
lstm2_fused(
    const float* __restrict__ x,      // [B, SEQ, 1]
    const float* __restrict__ w_ih0,  // [256, 1]
    const float* __restrict__ w_hh0,  // [256, 64]
    const float* __restrict__ b_ih0,  // [256]
    const float* __restrict__ b_hh0,  // [256]
    const float* __restrict__ w_ih1,  // [256, 64]
    const float* __restrict__ w_hh1,  // [256, 64]
    const float* __restrict__ b_ih1,  // [256]
    const float* __restrict__ b_hh1,  // [256]
    const float* __restrict__ fc_w,   // [12, 64]
    const float* __restrict__ fc_b,   // [12]
    float* __restrict__ out)          // [B, 12]
{
    __shared__ float xs[BT][SEQ];    // 8 KB
    __shared__ float h0s[BT][HID];   // 1 KB
    __shared__ float h1s[BT][HID];   // 1 KB
    __shared__ float gs0[BT][G4];    // 4 KB  gates layer0, step t+1
    __shared__ float gs1[BT][G4];    // 4 KB  gates layer1, step t

    const int tid = threadIdx.x;
    const int g   = tid;              // gate row owned by this thread
    const int b0  = blockIdx.x * BT;

    // ---- loop-invariant weights as SSA vectors (12 x v16f = 192 regs, VGPR+AGPR) ----
    v16f w0_0 = {}, w0_1 = {}, w0_2 = {}, w0_3 = {};
    v16f wi_0 = {}, wi_1 = {}, wi_2 = {}, wi_3 = {};
    v16f w1_0 = {}, w1_1 = {}, w1_2 = {}, w1_3 = {};
    LOAD_ROW(w_hh0, w0_0, w0_1, w0_2, w0_3);
    LOAD_ROW(w_ih1, wi_0, wi_1, wi_2, wi_3);
    LOAD_ROW(w_hh1, w1_0, w1_1, w1_2, w1_3);

    const float wih0g = w_ih0[g];                    // input size == 1
    const float bias0 = b_ih0[g] + b_hh0[g];
    const float bias1 = b_ih1[g] + b_hh1[g];

    // ---- stage this block's x tile into LDS ----
    for (int i = tid; i < BT * SEQ; i += 256) {
        int b = i >> 9, t = i & (SEQ - 1);
        xs[b][t] = x[(size_t)(b0 + b) * SEQ + t];
    }
    for (int i = tid; i < BT * HID; i += 256) {
        ((float*)h0s)[i] = 0.f;
        ((float*)h1s)[i] = 0.f;
    }
    const int eb = tid >> 6;     // batch in tile (elementwise phase)
    const int ej = tid & 63;     // hidden unit   (elementwise phase)
    float c0 = 0.f, c1 = 0.f;
    __syncthreads();

    // ===== prologue: gates0(0) = bias0 + x[0]*w_ih0  (h0 init = 0) =====
#pragma unroll
    for (int b = 0; b < BT; ++b) gs0[b][g] = fmaf(xs[b][0], wih0g, bias0);
    __syncthreads();
    {   // ew0 -> h0(0), c0(0)
        float ig = sigf(gs0[eb][ej]);
        float fg = sigf(gs0[eb][64 + ej]);
        float gg = tanhf_fast(gs0[eb][128 + ej]);
        float og = sigf(gs0[eb][192 + ej]);
        c0 = fg * c0 + ig * gg;
        h0s[eb][ej] = og * tanhf_fast(c0);
    }
    __syncthreads();

    for (int t = 0; t < SEQ; ++t) {
        const int tx = (t + 1 < SEQ) ? (t + 1) : (SEQ - 1);  // clamped dummy at t=511
        float a0[BT], a1[BT];
        // ===== merged gemm phase =====
        // a0[b] = gates0(t+1)[g] = bias0 + x[t+1]*w_ih0[g] + h0(t) . w_hh0[g]
        // a1[b] = gates1(t)[g]   = bias1 + h0(t) . w_ih1[g] + h1(t-1) . w_hh1[g]
#pragma unroll
        for (int b = 0; b < BT; ++b) {
            a0[b] = fmaf(xs[b][tx], wih0g, bias0);
            a1[b] = bias1;
        }
#pragma unroll
        for (int c = 0; c < 4; ++c) {
            v16f& W0c = (c == 0) ? w0_0 : (c == 1) ? w0_1 : (c == 2) ? w0_2 : w0_3;
            v16f& WIc = (c == 0) ? wi_0 : (c == 1) ? wi_1 : (c == 2) ? wi_2 : wi_3;
            v16f& W1c = (c == 0) ? w1_0 : (c == 1) ? w1_1 : (c == 2) ? w1_2 : w1_3;
#pragma unroll
            for (int i = 0; i < 16; i += 4) {
#pragma unroll
                for (int b = 0; b < BT; ++b) {
                    float4 h0v = *(const float4*)&h0s[b][c * 16 + i];  // read ONCE, feeds 8 FMAs
                    float4 h1v = *(const float4*)&h1s[b][c * 16 + i];
                    a0[b] = fmaf(h0v.x, W0c[i + 0], a0[b]);
                    a0[b] = fmaf(h0v.y, W0c[i + 1], a0[b]);
                    a0[b] = fmaf(h0v.z, W0c[i + 2], a0[b]);
                    a0[b] = fmaf(h0v.w, W0c[i + 3], a0[b]);
                    a1[b] = fmaf(h0v.x, WIc[i + 0], a1[b]);
                    a1[b] = fmaf(h0v.y, WIc[i + 1], a1[b]);
                    a1[b] = fmaf(h0v.z, WIc[i + 2], a1[b]);
                    a1[b] = fmaf(h0v.w, WIc[i + 3], a1[b]);
                    a1[b] = fmaf(h1v.x, W1c[i + 0], a1[b]);
                    a1[b] = fmaf(h1v.y, W1c[i + 1], a1[b]);
                    a1[b] = fmaf(h1v.z, W1c[i + 2], a1[b]);
                    a1[b] = fmaf(h1v.w, W1c[i + 3], a1[b]);
                }
            }
        }
#pragma unroll
        for (int b = 0; b < BT; ++b) { gs0[b][g] = a0[b]; gs1[b][g] = a1[b]; }
        __syncthreads();

        // ===== merged elementwise phase: ew0(t+1) and ew1(t) =====
        {
            float ig = sigf(gs0[eb][ej]);
            float fg = sigf(gs0[eb][64 + ej]);
            float gg = tanhf_fast(gs0[eb][128 + ej]);
            float og = sigf(gs0[eb][192 + ej]);
            c0 = fg * c0 + ig * gg;
            h0s[eb][ej] = og * tanhf_fast(c0);

            float ig1 = sigf(gs1[eb][ej]);
            float fg1 = sigf(gs1[eb][64 + ej]);
            float gg1 = tanhf_fast(gs1[eb][128 + ej]);
            float og1 = sigf(gs1[eb][192 + ej]);
            c1 = fg1 * c1 + ig1 * gg1;
            h1s[eb][ej] = og1 * tanhf_fast(c1);
        }
        __syncthreads();
    }

    // ===== final projection: out[b][o] = fc_b[o] + h1(511) . fc_w[o] =====
    if (tid < BT * NOUT) {
        int b = tid / NOUT, o = tid % NOUT;
        float acc = fc_b[o];
#pragma unroll
        for (int j = 0; j < HID; ++j)
            acc = fmaf(fc_w[o * HID + j], h1s[b][j], acc);
        out[(size_t)(b0 + b) * NOUT + o] = acc;
    }
}

extern "C" void kernel_launch(void* const* d_in, const int* in_sizes, int n_in,
                              void* d_out, int out_size, void* d_ws, size_t ws_size,
                              hipStream_t stream) {
    const float* x     = (const float*)d_in[0];
    const float* w_ih0 = (const float*)d_in[1];
    const float* w_hh0 = (const float*)d_in[2];
    const float* b_ih0 = (const float*)d_in[3];
    const float* b_hh0 = (const float*)d_in[4];
    const float* w_ih1 = (const float*)d_in[5];
    const float* w_hh1 = (const float*)d_in[6];
    const float* b_ih1 = (const float*)d_in[7];
    const float* b_hh1 = (const float*)d_in[8];
    const float* fc_w  = (const float*)d_in[9];
    const float* fc_b  = (const float*)d_in[10];

    const int B = in_sizes[0] / SEQ;          // 2048
    dim3 grid(B / BT);                        // 512 blocks -> 2 blocks/CU
    lstm2_fused<<<grid, 256, 0, stream>>>(x, w_ih0, w_hh0, b_ih0, b_hh0,
                                          w_ih1, w_hh1, b_ih1, b_hh1,
                                          fc_w, fc_b, (float*)d_out);
}